// Round 1
// baseline (981.359 us; speedup 1.0000x reference)
//
#include <hip/hip_runtime.h>
#include <stdint.h>

// Problem constants
#define NB 768          // ntiles*N*f = 16*8*6 rows
#define LTILE 334       // positions per row
#define LOUT 315        // 334 - 20 + 1
#define KF 20           // motif length
#define AA 21           // alphabet
#define UU 600          // profiles
#define S_SIZE 76800    // 16*8*600
#define R_SIZE 252000   // 20*21*600

// workspace layout (bytes)
#define WS_IDS_OFF 504064                    // after Rb (252000*2 -> pad)
#define WS_PS_OFF  (504064 + 258048)         // after ids (768*336)

// ---------------- kernel 1: R = log(max(P/Q, eps)), fp32 out + bf16 copy ---
__global__ __launch_bounds__(256) void prep_R(const float* __restrict__ P,
                                              const float* __restrict__ Q,
                                              float* __restrict__ Rout,
                                              uint16_t* __restrict__ Rb) {
  int i = blockIdx.x * 256 + threadIdx.x;
  if (i >= R_SIZE) return;
  int a = (i / UU) % AA;
  float v = logf(fmaxf(P[i] / Q[a], 1e-6f));
  Rout[i] = v;
  // round-to-nearest-even bf16
  uint32_t x = __float_as_uint(v);
  uint32_t r = (x + 0x7fffu + ((x >> 16) & 1u)) >> 16;
  Rb[i] = (uint16_t)r;
}

// ---------------- kernel 2: one-hot -> letter ids (bytes, rows padded to 336)
__global__ __launch_bounds__(256) void prep_ids(const float* __restrict__ X,
                                                uint8_t* __restrict__ ids) {
  int b = blockIdx.x;
  for (int pos = threadIdx.x; pos < 336; pos += 256) {
    uint8_t id = 0;
    if (pos < LTILE) {
      const float* xp = X + ((size_t)b * LTILE + pos) * AA;
#pragma unroll
      for (int a = 0; a < AA; a++)
        if (xp[a] > 0.5f) id = (uint8_t)a;
    }
    ids[b * 336 + pos] = id;  // bytes 334/335 -> 0 (window padding)
  }
}

// ---------------- kernel 3: Z gather + per-(b,u) partial max ---------------
// grid = (768, 10); block = 256 = 8 u-octs x 32 l-groups; u-chunk = 64.
// LDS: R slice [20][21][64u] in bf16, row stride padded 64->72 ushorts (144 B)
// so the data-dependent row index doesn't alias LDS banks.
__global__ __launch_bounds__(256) void zmain(const uint16_t* __restrict__ Rb,
                                             const uint8_t* __restrict__ ids,
                                             float* __restrict__ Z,
                                             float* __restrict__ pS) {
  __shared__ uint16_t Rl[420 * 72];  // 60480 B
  __shared__ uint8_t idl[336];
  int b = blockIdx.x;
  int u0 = blockIdx.y * 64;
  int uw = min(64, UU - u0);   // 64, last chunk 24
  int tid = threadIdx.x;

  // stage R slice: rows (w,c) of uw bf16 each, 16B segments
  int nseg = uw >> 3;          // 8 or 3
  for (int i = tid; i < 420 * nseg; i += 256) {
    int row = i / nseg, seg = i - row * nseg;
    const uint4* src = (const uint4*)(Rb + row * UU + u0 + seg * 8);
    *(uint4*)(&Rl[row * 72 + seg * 8]) = *src;
  }
  for (int i = tid; i < 84; i += 256)
    ((uint32_t*)idl)[i] = ((const uint32_t*)(ids + b * 336))[i];
  __syncthreads();

  int uoct = tid >> 5;   // 0..7 : which 8 u's
  int lgrp = tid & 31;   // 0..31: which l block
  if (uoct * 8 >= uw) return;          // idle octs in tail chunk (no more barriers)
  int uoff = uoct * 8;

  float smax[8];
#pragma unroll
  for (int k = 0; k < 8; k++) smax[k] = -3.4e38f;

  float* Zb = Z + (size_t)b * (LOUT * UU) + u0 + uoff;

  for (int jj = 0; jj < 3; jj++) {
    int l0 = jj * 128 + lgrp * 4;      // 4 consecutive l per thread per pass
    if (l0 >= LOUT) break;
    // ids window l0..l0+23 into 6 dwords (constant-offset byte extracts below)
    uint32_t idw[6];
#pragma unroll
    for (int d = 0; d < 6; d++)
      idw[d] = *(const uint32_t*)(&idl[l0 + 4 * d]);

    float acc[4][8];
#pragma unroll
    for (int g = 0; g < 4; g++)
#pragma unroll
      for (int k = 0; k < 8; k++) acc[g][k] = 0.0f;

#pragma unroll
    for (int w = 0; w < KF; w++) {
#pragma unroll
      for (int g = 0; g < 4; g++) {
        int p = w + g;
        uint32_t c = (idw[p >> 2] >> ((p & 3) * 8)) & 0xFFu;
        const uint4 rv = *(const uint4*)(&Rl[(w * 21 + c) * 72 + uoff]);
        acc[g][0] += __uint_as_float(rv.x << 16);
        acc[g][1] += __uint_as_float(rv.x & 0xffff0000u);
        acc[g][2] += __uint_as_float(rv.y << 16);
        acc[g][3] += __uint_as_float(rv.y & 0xffff0000u);
        acc[g][4] += __uint_as_float(rv.z << 16);
        acc[g][5] += __uint_as_float(rv.z & 0xffff0000u);
        acc[g][6] += __uint_as_float(rv.w << 16);
        acc[g][7] += __uint_as_float(rv.w & 0xffff0000u);
      }
    }
#pragma unroll
    for (int g = 0; g < 4; g++) {
      int l = l0 + g;
      if (l < LOUT) {
        float* zp = Zb + (size_t)l * UU;
        float4 a0 = make_float4(acc[g][0], acc[g][1], acc[g][2], acc[g][3]);
        float4 a1 = make_float4(acc[g][4], acc[g][5], acc[g][6], acc[g][7]);
        *(float4*)zp = a0;
        *(float4*)(zp + 4) = a1;
#pragma unroll
        for (int k = 0; k < 8; k++) smax[k] = fmaxf(smax[k], acc[g][k]);
      }
    }
  }

  // reduce max over the 32 l-groups (same uoct == same 32-lane subgroup)
#pragma unroll
  for (int k = 0; k < 8; k++) {
    float v = smax[k];
#pragma unroll
    for (int off = 16; off >= 1; off >>= 1)
      v = fmaxf(v, __shfl_down(v, off, 32));
    if (lgrp == 0) pS[b * UU + u0 + uoff + k] = v;
  }
}

// ---------------- kernel 4: S = max over f of partial maxes ----------------
__global__ __launch_bounds__(256) void finalS(const float* __restrict__ pS,
                                              float* __restrict__ S) {
  int i = blockIdx.x * 256 + threadIdx.x;
  if (i >= S_SIZE) return;
  int u = i % UU;
  int tn = i / UU;
  float m = -3.4e38f;
#pragma unroll
  for (int f = 0; f < 6; f++) m = fmaxf(m, pS[(tn * 6 + f) * UU + u]);
  S[i] = m;
}

extern "C" void kernel_launch(void* const* d_in, const int* in_sizes, int n_in,
                              void* d_out, int out_size, void* d_ws, size_t ws_size,
                              hipStream_t stream) {
  const float* X = (const float*)d_in[0];
  const float* P = (const float*)d_in[1];
  const float* Q = (const float*)d_in[2];
  float* S = (float*)d_out;
  float* R = S + S_SIZE;
  float* Z = R + R_SIZE;
  uint16_t* Rb = (uint16_t*)d_ws;
  uint8_t* ids = (uint8_t*)d_ws + WS_IDS_OFF;
  float* pS = (float*)((uint8_t*)d_ws + WS_PS_OFF);

  hipLaunchKernelGGL(prep_R, dim3((R_SIZE + 255) / 256), dim3(256), 0, stream,
                     P, Q, R, Rb);
  hipLaunchKernelGGL(prep_ids, dim3(NB), dim3(256), 0, stream, X, ids);
  hipLaunchKernelGGL(zmain, dim3(NB, 10), dim3(256), 0, stream, Rb, ids, Z, pS);
  hipLaunchKernelGGL(finalS, dim3((S_SIZE + 255) / 256), dim3(256), 0, stream,
                     pS, S);
}